// Round 1
// baseline (2142.032 us; speedup 1.0000x reference)
//
#include <hip/hip_runtime.h>
#include <stdint.h>

#define HH 128
#define WW 128
#define CHN 16
#define NPIX (HH*WW)          // 16384 per batch
#define PLANE (CHN*NPIX)      // 262144 per batch
#define STEPS 64
#define TW 16
#define TH 8

// RNG mode: 1 = jax_threefry_partitionable (default in modern JAX),
//           0 = legacy/original counter scheme. Flip if absmax is O(1).
#define RNG_PARTITIONABLE 1

__host__ __device__ __forceinline__ uint32_t rotl32_(uint32_t x, int d) {
  return (x << d) | (x >> (32 - d));
}

__host__ __device__ __forceinline__ void tf2x32(uint32_t k0, uint32_t k1,
                                                uint32_t x0, uint32_t x1,
                                                uint32_t* o0, uint32_t* o1) {
  uint32_t ks0 = k0, ks1 = k1, ks2 = k0 ^ k1 ^ 0x1BD11BDAu;
  x0 += ks0; x1 += ks1;
  // round group 1 (13,15,26,6)
  x0 += x1; x1 = rotl32_(x1, 13); x1 ^= x0;
  x0 += x1; x1 = rotl32_(x1, 15); x1 ^= x0;
  x0 += x1; x1 = rotl32_(x1, 26); x1 ^= x0;
  x0 += x1; x1 = rotl32_(x1, 6);  x1 ^= x0;
  x0 += ks1; x1 += ks2 + 1u;
  // group 2 (17,29,16,24)
  x0 += x1; x1 = rotl32_(x1, 17); x1 ^= x0;
  x0 += x1; x1 = rotl32_(x1, 29); x1 ^= x0;
  x0 += x1; x1 = rotl32_(x1, 16); x1 ^= x0;
  x0 += x1; x1 = rotl32_(x1, 24); x1 ^= x0;
  x0 += ks2; x1 += ks0 + 2u;
  // group 3 (13,15,26,6)
  x0 += x1; x1 = rotl32_(x1, 13); x1 ^= x0;
  x0 += x1; x1 = rotl32_(x1, 15); x1 ^= x0;
  x0 += x1; x1 = rotl32_(x1, 26); x1 ^= x0;
  x0 += x1; x1 = rotl32_(x1, 6);  x1 ^= x0;
  x0 += ks0; x1 += ks1 + 3u;
  // group 4 (17,29,16,24)
  x0 += x1; x1 = rotl32_(x1, 17); x1 ^= x0;
  x0 += x1; x1 = rotl32_(x1, 29); x1 ^= x0;
  x0 += x1; x1 = rotl32_(x1, 16); x1 ^= x0;
  x0 += x1; x1 = rotl32_(x1, 24); x1 ^= x0;
  x0 += ks1; x1 += ks2 + 4u;
  // group 5 (13,15,26,6)
  x0 += x1; x1 = rotl32_(x1, 13); x1 ^= x0;
  x0 += x1; x1 = rotl32_(x1, 15); x1 ^= x0;
  x0 += x1; x1 = rotl32_(x1, 26); x1 ^= x0;
  x0 += x1; x1 = rotl32_(x1, 6);  x1 ^= x0;
  x0 += ks2; x1 += ks0 + 5u;
  *o0 = x0; *o1 = x1;
}

// --- prep: transpose w1 (48 x 128) -> w1t (128 x 48) so per-j rows are contiguous
__global__ void prep_w1t(const float* __restrict__ w1, float* __restrict__ w1t) {
  int i = blockIdx.x * 256 + threadIdx.x;
  if (i < 48 * 128) {
    int j = i / 48, k = i % 48;
    w1t[i] = w1[k * 128 + j];
  }
}

// --- K1: pre-life, perceive conv, 48->128 relu, 128->16, stochastic update.
// Writes x_tilde (updated-but-unmasked state) and prelife plane.
__global__ __launch_bounds__(256) void nca_step1(
    const float* __restrict__ xin, const float* __restrict__ pw,
    const float* __restrict__ w1t, const float* __restrict__ b1,
    const float* __restrict__ w2, float* __restrict__ xtld,
    float* __restrict__ prelife, uint32_t k0, uint32_t k1)
{
  __shared__ float xt[CHN][TH + 2][TW + 2];
  __shared__ float dbuf[128][17];   // padded to kill bank conflicts

  const int tid = threadIdx.x;
  const int bx = blockIdx.x;        // tile col: 0..7
  const int by = blockIdx.y;        // tile row: 0..15
  const int b  = blockIdx.z;        // batch: 0..1
  const int h0 = by * TH, w0 = bx * TW;

  // stage x tile + halo (zero-padded; zero vs -inf is equivalent for >0.1 test)
  const float* xb = xin + (size_t)b * PLANE;
  for (int i = tid; i < CHN * (TH + 2) * (TW + 2); i += 256) {
    int c  = i / ((TH + 2) * (TW + 2));
    int r  = (i / (TW + 2)) % (TH + 2);
    int cc = i % (TW + 2);
    int gh = h0 + r - 1, gw = w0 + cc - 1;
    float v = 0.f;
    if (gh >= 0 && gh < HH && gw >= 0 && gw < WW) v = xb[(c * HH + gh) * WW + gw];
    xt[c][r][cc] = v;
  }
  __syncthreads();

  const int wv   = __builtin_amdgcn_readfirstlane((int)threadIdx.x) >> 6; // wave id (uniform)
  const int lane = tid & 63;
  const int pix  = (wv & 1) * 64 + lane;   // 0..127: pixel within tile
  const int jbase = (wv >> 1) * 64;        // hidden-dim half (wave-uniform)
  const int pr = pix >> 4, pc = pix & 15;
  const int lr = pr + 1, lc = pc + 1;

  // build comb = [x(16) ; p(32)] in registers; p[2c],p[2c+1] from channel c
  float comb[48];
  float premax = -1e30f;
  #pragma unroll
  for (int c = 0; c < CHN; ++c) {
    float n[9];
    #pragma unroll
    for (int dy = 0; dy < 3; ++dy)
      #pragma unroll
      for (int dx = 0; dx < 3; ++dx)
        n[dy * 3 + dx] = xt[c][lr + dy - 1][lc + dx - 1];
    comb[c] = n[4];
    float p0 = 0.f, p1 = 0.f;
    #pragma unroll
    for (int i = 0; i < 9; ++i) {
      p0 = fmaf(pw[(2 * c) * 9 + i], n[i], p0);
      p1 = fmaf(pw[(2 * c + 1) * 9 + i], n[i], p1);
    }
    comb[16 + 2 * c] = p0;
    comb[17 + 2 * c] = p1;
    if (c == 3) {
      float m = n[0];
      #pragma unroll
      for (int i = 1; i < 9; ++i) m = fmaxf(m, n[i]);
      premax = m;
    }
  }

  // matmuls: this wave handles j in [jbase, jbase+64)
  float delta[16];
  #pragma unroll
  for (int c = 0; c < 16; ++c) delta[c] = 0.f;
  for (int jj = 0; jj < 64; ++jj) {
    const int j = jbase + jj;                 // wave-uniform -> scalar loads
    const float* wr = w1t + j * 48;
    float hj = b1[j];
    #pragma unroll
    for (int k = 0; k < 48; ++k) hj = fmaf(comb[k], wr[k], hj);
    hj = fmaxf(hj, 0.f);
    const float* w2r = w2 + j * 16;
    #pragma unroll
    for (int c = 0; c < 16; ++c) delta[c] = fmaf(hj, w2r[c], delta[c]);
  }

  // reduce the two j-halves (waves 2,3 -> waves 0,1)
  if (wv >> 1) {
    #pragma unroll
    for (int c = 0; c < 16; ++c) dbuf[pix][c] = delta[c];
  }
  __syncthreads();
  if (!(wv >> 1)) {
    #pragma unroll
    for (int c = 0; c < 16; ++c) delta[c] += dbuf[pix][c];

    const int gh = h0 + pr, gw = w0 + pc;
    const int gidx = gh * WW + gw;

    uint32_t bits;
#if RNG_PARTITIONABLE
    { uint32_t o0, o1;
      tf2x32(k0, k1, 0u, (uint32_t)(b * NPIX + gidx), &o0, &o1);
      bits = o0 ^ o1; }
#else
    { uint32_t o0, o1;
      tf2x32(k0, k1, (uint32_t)gidx, (uint32_t)(NPIX + gidx), &o0, &o1);
      bits = (b == 0) ? o0 : o1; }
#endif
    // uniform<0.5  <=>  MSB of bits == 0 ; alpha (pre-update) > 0.1
    const float u = (((bits >> 31) == 0u) && (comb[3] > 0.1f)) ? 1.f : 0.f;

    float* qb = xtld + (size_t)b * PLANE;
    #pragma unroll
    for (int c = 0; c < CHN; ++c)
      qb[c * NPIX + gidx] = fmaf(delta[c], u, comb[c]);
    prelife[b * NPIX + gidx] = (premax > 0.1f) ? 1.f : 0.f;
  }
}

// --- K2: post-update life mask and multiply
__global__ __launch_bounds__(256) void nca_step2(
    const float* __restrict__ xtld, const float* __restrict__ prelife,
    float* __restrict__ xout)
{
  const int g = blockIdx.x * 256 + threadIdx.x;   // 0..32767
  const int b = g >> 14, hw = g & (NPIX - 1);
  const int h = hw >> 7, w = hw & 127;
  const float* qb = xtld + (size_t)b * PLANE;
  const float* ap = qb + 3 * NPIX;
  float m = -1e30f;
  #pragma unroll
  for (int dy = -1; dy <= 1; ++dy) {
    int hh = h + dy; if (hh < 0 || hh >= HH) continue;
    #pragma unroll
    for (int dx = -1; dx <= 1; ++dx) {
      int ww2 = w + dx; if (ww2 < 0 || ww2 >= WW) continue;
      m = fmaxf(m, ap[hh * WW + ww2]);
    }
  }
  const float life = (m > 0.1f && prelife[g] > 0.5f) ? 1.f : 0.f;
  float* ob = xout + (size_t)b * PLANE;
  #pragma unroll
  for (int c = 0; c < CHN; ++c)
    ob[c * NPIX + hw] = qb[c * NPIX + hw] * life;
}

extern "C" void kernel_launch(void* const* d_in, const int* in_sizes, int n_in,
                              void* d_out, int out_size, void* d_ws, size_t ws_size,
                              hipStream_t stream) {
  (void)in_sizes; (void)n_in; (void)out_size; (void)ws_size;
  const float* x  = (const float*)d_in[0];
  const float* pw = (const float*)d_in[1];
  const float* w1 = (const float*)d_in[2];
  const float* b1 = (const float*)d_in[3];
  const float* w2 = (const float*)d_in[4];
  // d_in[5] = steps (==64 per setup_inputs); fixed at compile time for graph capture.

  float* out = (float*)d_out;           // doubles as the persistent state buffer
  float* ws  = (float*)d_ws;
  float* bufQ    = ws;                  // 2*PLANE floats: x_tilde
  float* prelife = ws + 2 * PLANE;      // 2*NPIX floats
  float* w1t     = ws + 2 * PLANE + 2 * NPIX;  // 6144 floats

  prep_w1t<<<(48 * 128 + 255) / 256, 256, 0, stream>>>(w1, w1t);

  // host-side key schedule for key(42) split into 64 step keys
  uint32_t key0[STEPS], key1[STEPS];
#if RNG_PARTITIONABLE
  for (uint32_t s = 0; s < STEPS; ++s)
    tf2x32(0u, 42u, 0u, s, &key0[s], &key1[s]);
#else
  {
    uint32_t a0[STEPS], a1[STEPS], flat[2 * STEPS];
    for (uint32_t i = 0; i < STEPS; ++i)
      tf2x32(0u, 42u, i, (uint32_t)STEPS + i, &a0[i], &a1[i]);
    for (int i = 0; i < STEPS; ++i) { flat[i] = a0[i]; flat[STEPS + i] = a1[i]; }
    for (int i = 0; i < STEPS; ++i) { key0[i] = flat[2 * i]; key1[i] = flat[2 * i + 1]; }
  }
#endif

  dim3 g1(WW / TW, HH / TH, 2);   // 8 x 16 x 2 = 256 blocks
  for (int s = 0; s < STEPS; ++s) {
    const float* src = (s == 0) ? x : out;
    nca_step1<<<g1, 256, 0, stream>>>(src, pw, w1t, b1, w2, bufQ, prelife,
                                      key0[s], key1[s]);
    nca_step2<<<(2 * NPIX) / 256, 256, 0, stream>>>(bufQ, prelife, out);
  }
}

// Round 2
// 1417.509 us; speedup vs baseline: 1.5111x; 1.5111x over previous
//
#include <hip/hip_runtime.h>
#include <stdint.h>

#define HH 128
#define WW 128
#define CHN 16
#define NPIX (HH*WW)          // 16384 per batch
#define PLANE (CHN*NPIX)      // 262144 per batch
#define STEPS 64
#define TW 8
#define TH 8

__host__ __device__ __forceinline__ uint32_t rotl32_(uint32_t x, int d) {
  return (x << d) | (x >> (32 - d));
}

__host__ __device__ __forceinline__ void tf2x32(uint32_t k0, uint32_t k1,
                                                uint32_t x0, uint32_t x1,
                                                uint32_t* o0, uint32_t* o1) {
  uint32_t ks0 = k0, ks1 = k1, ks2 = k0 ^ k1 ^ 0x1BD11BDAu;
  x0 += ks0; x1 += ks1;
  x0 += x1; x1 = rotl32_(x1, 13); x1 ^= x0;
  x0 += x1; x1 = rotl32_(x1, 15); x1 ^= x0;
  x0 += x1; x1 = rotl32_(x1, 26); x1 ^= x0;
  x0 += x1; x1 = rotl32_(x1, 6);  x1 ^= x0;
  x0 += ks1; x1 += ks2 + 1u;
  x0 += x1; x1 = rotl32_(x1, 17); x1 ^= x0;
  x0 += x1; x1 = rotl32_(x1, 29); x1 ^= x0;
  x0 += x1; x1 = rotl32_(x1, 16); x1 ^= x0;
  x0 += x1; x1 = rotl32_(x1, 24); x1 ^= x0;
  x0 += ks2; x1 += ks0 + 2u;
  x0 += x1; x1 = rotl32_(x1, 13); x1 ^= x0;
  x0 += x1; x1 = rotl32_(x1, 15); x1 ^= x0;
  x0 += x1; x1 = rotl32_(x1, 26); x1 ^= x0;
  x0 += x1; x1 = rotl32_(x1, 6);  x1 ^= x0;
  x0 += ks0; x1 += ks1 + 3u;
  x0 += x1; x1 = rotl32_(x1, 17); x1 ^= x0;
  x0 += x1; x1 = rotl32_(x1, 29); x1 ^= x0;
  x0 += x1; x1 = rotl32_(x1, 16); x1 ^= x0;
  x0 += x1; x1 = rotl32_(x1, 24); x1 ^= x0;
  x0 += ks1; x1 += ks2 + 4u;
  x0 += x1; x1 = rotl32_(x1, 13); x1 ^= x0;
  x0 += x1; x1 = rotl32_(x1, 15); x1 ^= x0;
  x0 += x1; x1 = rotl32_(x1, 26); x1 ^= x0;
  x0 += x1; x1 = rotl32_(x1, 6);  x1 ^= x0;
  x0 += ks2; x1 += ks0 + 5u;
  *o0 = x0; *o1 = x1;
}

// --- prep: transpose w1 (48 x 128) -> w1t (128 x 48)
__global__ void prep_w1t(const float* __restrict__ w1, float* __restrict__ w1t) {
  int i = blockIdx.x * 256 + threadIdx.x;
  if (i < 48 * 128) {
    int j = i / 48, k = i % 48;
    w1t[i] = w1[k * 128 + j];
  }
}

// --- K1: pre-life, perceive conv, 48->128 relu, 128->16, stochastic update.
// 8x8 pixel tile per block; 4 waves each own 32 hidden units; LDS reduce.
__global__ __launch_bounds__(256, 2) void nca_step1(
    const float* __restrict__ xin, const float* __restrict__ pw,
    const float* __restrict__ w1t, const float* __restrict__ b1,
    const float* __restrict__ w2, float* __restrict__ xtld,
    float* __restrict__ prelife, uint32_t k0, uint32_t k1)
{
  __shared__ float xt[CHN][TH + 2][TW + 2];
  __shared__ float dbuf[3][64][17];   // padded: lane stride 17 -> conflict-free

  const int tid = threadIdx.x;
  const int bx = blockIdx.x;        // tile col: 0..15
  const int by = blockIdx.y;        // tile row: 0..15
  const int b  = blockIdx.z;        // batch
  const int h0 = by * TH, w0 = bx * TW;

  // stage x tile + 1-halo (zero-pad ok: verdict of >0.1 unchanged vs -inf)
  const float* xb = xin + (size_t)b * PLANE;
  for (int i = tid; i < CHN * (TH + 2) * (TW + 2); i += 256) {
    int c  = i / ((TH + 2) * (TW + 2));
    int r  = (i / (TW + 2)) % (TH + 2);
    int cc = i % (TW + 2);
    int gh = h0 + r - 1, gw = w0 + cc - 1;
    float v = 0.f;
    if (gh >= 0 && gh < HH && gw >= 0 && gw < WW) v = xb[(c * HH + gh) * WW + gw];
    xt[c][r][cc] = v;
  }
  __syncthreads();

  const int wv   = __builtin_amdgcn_readfirstlane((int)threadIdx.x) >> 6;
  const int lane = tid & 63;
  const int pr = lane >> 3, pc = lane & 7;   // pixel within 8x8 tile
  const int jbase = wv * 32;                 // hidden-dim quarter (uniform)

  // comb = [x(16) ; p(32)]: depthwise sobel pair per channel
  float comb[48];
  float premax = -1e30f;
  #pragma unroll
  for (int c = 0; c < CHN; ++c) {
    float n[9];
    #pragma unroll
    for (int dy = 0; dy < 3; ++dy)
      #pragma unroll
      for (int dx = 0; dx < 3; ++dx)
        n[dy * 3 + dx] = xt[c][pr + dy][pc + dx];
    comb[c] = n[4];
    float p0 = 0.f, p1 = 0.f;
    #pragma unroll
    for (int i = 0; i < 9; ++i) {
      p0 = fmaf(pw[(2 * c) * 9 + i], n[i], p0);
      p1 = fmaf(pw[(2 * c + 1) * 9 + i], n[i], p1);
    }
    comb[16 + 2 * c] = p0;
    comb[17 + 2 * c] = p1;
    if (c == 3) {
      float m = n[0];
      #pragma unroll
      for (int i = 1; i < 9; ++i) m = fmaxf(m, n[i]);
      premax = m;
    }
  }
  // pin comb into VGPRs — R1 showed the allocator demoting it (VGPR_Count=40)
  #pragma unroll
  for (int k = 0; k < 48; ++k) asm volatile("" : "+v"(comb[k]));

  // this wave: j in [jbase, jbase+32), unrolled x2 for ILP
  float delta[16];
  #pragma unroll
  for (int c = 0; c < 16; ++c) delta[c] = 0.f;
  for (int jj = 0; jj < 32; jj += 2) {
    const int j0 = jbase + jj;
    const float* wr0 = w1t + j0 * 48;
    const float* wr1 = wr0 + 48;
    float h0 = b1[j0], h1 = b1[j0 + 1];
    #pragma unroll
    for (int k = 0; k < 48; ++k) {
      h0 = fmaf(comb[k], wr0[k], h0);
      h1 = fmaf(comb[k], wr1[k], h1);
    }
    h0 = fmaxf(h0, 0.f); h1 = fmaxf(h1, 0.f);
    const float* w20 = w2 + j0 * 16;
    const float* w21 = w20 + 16;
    #pragma unroll
    for (int c = 0; c < 16; ++c)
      delta[c] = fmaf(h0, w20[c], fmaf(h1, w21[c], delta[c]));
  }

  // reduce the 4 j-quarters
  if (wv) {
    #pragma unroll
    for (int c = 0; c < 16; ++c) dbuf[wv - 1][lane][c] = delta[c];
  }
  __syncthreads();
  if (wv == 0) {
    #pragma unroll
    for (int t = 0; t < 3; ++t)
      #pragma unroll
      for (int c = 0; c < 16; ++c) delta[c] += dbuf[t][lane][c];

    const int gh = h0 + pr, gw = w0 + pc;
    const int gidx = gh * WW + gw;

    uint32_t o0, o1;
    tf2x32(k0, k1, 0u, (uint32_t)(b * NPIX + gidx), &o0, &o1);
    const uint32_t bits = o0 ^ o1;
    // uniform<0.5 <=> MSB==0 ; gate on pre-update alpha > 0.1
    const float u = (((bits >> 31) == 0u) && (comb[3] > 0.1f)) ? 1.f : 0.f;

    float* qb = xtld + (size_t)b * PLANE;
    #pragma unroll
    for (int c = 0; c < CHN; ++c)
      qb[c * NPIX + gidx] = fmaf(delta[c], u, comb[c]);
    prelife[b * NPIX + gidx] = (premax > 0.1f) ? 1.f : 0.f;
  }
}

// --- K2: post-update life mask and multiply
__global__ __launch_bounds__(256) void nca_step2(
    const float* __restrict__ xtld, const float* __restrict__ prelife,
    float* __restrict__ xout)
{
  const int g = blockIdx.x * 256 + threadIdx.x;   // 0..32767
  const int b = g >> 14, hw = g & (NPIX - 1);
  const int h = hw >> 7, w = hw & 127;
  const float* qb = xtld + (size_t)b * PLANE;
  const float* ap = qb + 3 * NPIX;
  float m = -1e30f;
  #pragma unroll
  for (int dy = -1; dy <= 1; ++dy) {
    int hh = h + dy; if (hh < 0 || hh >= HH) continue;
    #pragma unroll
    for (int dx = -1; dx <= 1; ++dx) {
      int ww2 = w + dx; if (ww2 < 0 || ww2 >= WW) continue;
      m = fmaxf(m, ap[hh * WW + ww2]);
    }
  }
  const float life = (m > 0.1f && prelife[g] > 0.5f) ? 1.f : 0.f;
  float* ob = xout + (size_t)b * PLANE;
  #pragma unroll
  for (int c = 0; c < CHN; ++c)
    ob[c * NPIX + hw] = qb[c * NPIX + hw] * life;
}

extern "C" void kernel_launch(void* const* d_in, const int* in_sizes, int n_in,
                              void* d_out, int out_size, void* d_ws, size_t ws_size,
                              hipStream_t stream) {
  (void)in_sizes; (void)n_in; (void)out_size; (void)ws_size;
  const float* x  = (const float*)d_in[0];
  const float* pw = (const float*)d_in[1];
  const float* w1 = (const float*)d_in[2];
  const float* b1 = (const float*)d_in[3];
  const float* w2 = (const float*)d_in[4];

  float* out = (float*)d_out;           // persistent state buffer
  float* ws  = (float*)d_ws;
  float* bufQ    = ws;                  // 2*PLANE floats: x_tilde
  float* prelife = ws + 2 * PLANE;      // 2*NPIX floats
  float* w1t     = ws + 2 * PLANE + 2 * NPIX;  // 6144 floats

  prep_w1t<<<(48 * 128 + 255) / 256, 256, 0, stream>>>(w1, w1t);

  // host-side key schedule: key(42) split into 64 step keys (partitionable)
  uint32_t key0[STEPS], key1[STEPS];
  for (uint32_t s = 0; s < STEPS; ++s)
    tf2x32(0u, 42u, 0u, s, &key0[s], &key1[s]);

  dim3 g1(WW / TW, HH / TH, 2);   // 16 x 16 x 2 = 512 blocks
  for (int s = 0; s < STEPS; ++s) {
    const float* src = (s == 0) ? x : out;
    nca_step1<<<g1, 256, 0, stream>>>(src, pw, w1t, b1, w2, bufQ, prelife,
                                      key0[s], key1[s]);
    nca_step2<<<(2 * NPIX) / 256, 256, 0, stream>>>(bufQ, prelife, out);
  }
}